// Round 7
// baseline (510.270 us; speedup 1.0000x reference)
//
#include <hip/hip_runtime.h>
#include <hip/hip_bf16.h>
#include <math.h>

// Problem constants (match reference setup_inputs)
static constexpr int Nn   = 50000;
static constexpr int Ee   = 1200000;
static constexpr int FIN  = 128;
static constexpr int HID  = 64;
static constexpr int NCLS = 40;

static constexpr int SCAN_BLOCKS = (Nn + 255) / 256;  // 196

typedef float f32x4  __attribute__((ext_vector_type(4)));
typedef short short8 __attribute__((ext_vector_type(8)));

__device__ inline unsigned short f2b(float f) {  // fp32 -> bf16 (RNE)
    unsigned int u = __builtin_bit_cast(unsigned int, f);
    return (unsigned short)((u + 0x7FFFu + ((u >> 16) & 1u)) >> 16);
}
__device__ inline float b2f(unsigned short h) {  // bf16 -> fp32
    return __builtin_bit_cast(float, (unsigned int)h << 16);
}

// ---------------------------------------------------------------------------
// CSR build step 1: count in-degree (int)
__global__ __launch_bounds__(256) void count_kernel(const int* __restrict__ dst,
                                                    int* __restrict__ cnt) {
    int e = blockIdx.x * 256 + threadIdx.x;
    if (e < Ee) atomicAdd(&cnt[dst[e]], 1);
}

// CSR build step 2a: per-block (256-elem) exclusive scan, coalesced loads.
// (R3 post-mortem: single-block strided scan was 127 us; hierarchical fix.)
__global__ __launch_bounds__(256) void scanA_kernel(const int* __restrict__ cnt,
                                                    int* __restrict__ rowptr,
                                                    int* __restrict__ bsum) {
    const int i    = blockIdx.x * 256 + threadIdx.x;
    const int lane = threadIdx.x & 63;
    const int wv   = threadIdx.x >> 6;
    int v = (i < Nn) ? cnt[i] : 0;
    int incl = v;
#pragma unroll
    for (int off = 1; off < 64; off <<= 1) {
        int t = __shfl_up(incl, off);
        if (lane >= off) incl += t;
    }
    __shared__ int wsum[4];
    if (lane == 63) wsum[wv] = incl;
    __syncthreads();
    int woff = 0;
#pragma unroll
    for (int w = 0; w < 4; ++w) woff += (w < wv) ? wsum[w] : 0;
    if (i < Nn) rowptr[i] = woff + incl - v;  // block-local exclusive
    if (threadIdx.x == 255) bsum[blockIdx.x] = woff + incl;
}

// CSR build step 2b: add block offsets, finalize rowptr and cursor.
__global__ __launch_bounds__(256) void scanC_kernel(int* __restrict__ rowptr,
                                                    const int* __restrict__ bsum,
                                                    int* __restrict__ cursor) {
    __shared__ int wsum[4];
    const int t    = threadIdx.x;
    const int lane = t & 63;
    const int wv   = t >> 6;
    int v = (t < blockIdx.x) ? bsum[t] : 0;  // blockIdx.x <= 195 < 256
#pragma unroll
    for (int off = 32; off; off >>= 1) v += __shfl_xor(v, off);
    if (lane == 0) wsum[wv] = v;
    __syncthreads();
    const int boff = wsum[0] + wsum[1] + wsum[2] + wsum[3];
    const int i = blockIdx.x * 256 + t;
    if (i < Nn) {
        int r = rowptr[i] + boff;
        rowptr[i] = r;
        cursor[i] = r;
    }
    if (blockIdx.x == 0 && t == 0) rowptr[Nn] = Ee;
}

// CSR build step 3: scatter edges into slots (single 8B store per edge).
// R6 post-mortem: XCD dst-partitioning FAILED (blockIdx%8 -> XCD ownership
// did not materialize; FETCH 7->56MB from 8x dst re-read, WRITE only
// 76->59MB). Reverted to the simple R5 form. The remaining ~76MB WRITE
// (1 line-event per edge) is structural to random-time slot claiming;
// a two-pass bucket sort is the queued fix if fill stays #1.
__global__ __launch_bounds__(256) void fill_kernel(
    const int* __restrict__ src, const int* __restrict__ dst,
    const float* __restrict__ ew, int* __restrict__ cursor,
    int2* __restrict__ edgeA) {
    int e = blockIdx.x * 256 + threadIdx.x;
    if (e < Ee) {
        int d = dst[e];
        int p = atomicAdd(&cursor[d], 1);
        edgeA[p] = make_int2(src[e], __builtin_bit_cast(int, ew[e]));
    }
}

// ---------------------------------------------------------------------------
// Fused dual GEMM: yl = bf16(x @ Wl) ; z = x @ Wr + b   (x: [n,K], W: [K,64])
// 16 rows/block, 256 threads. k-loop kept rolled to avoid register spills
// (R1 post-mortem: full unroll -> 256 VGPR + 862MB scratch traffic).
// yl stored bf16: halves gather-side read traffic (R6 theory).
template <int K>
__global__ __launch_bounds__(256, 4) void gemm2_kernel(
    const float* __restrict__ x, const float* __restrict__ Wl,
    const float* __restrict__ Wr, const float* __restrict__ b,
    unsigned short* __restrict__ yl, float* __restrict__ z) {
    __shared__ float w_s[2][64 * 64];  // 32 KB
    __shared__ float x_s[16][K];
    const int col  = threadIdx.x & 63;
    const int half = (threadIdx.x >> 6) & 1;  // 0 -> yl, 1 -> z
    const int rh   = threadIdx.x >> 7;        // 0..1
    const int row0 = blockIdx.x * 16;

    for (int i = threadIdx.x; i < 16 * K; i += 256) {
        int r = i / K, c = i % K;
        x_s[r][c] = x[(row0 + r) * K + c];
    }

    float acc[8];
#pragma unroll
    for (int i = 0; i < 8; ++i) acc[i] = 0.f;

    for (int kt = 0; kt < K; kt += 64) {
        __syncthreads();
        for (int i = threadIdx.x; i < 64 * 64; i += 256) {
            int kr = i >> 6, kc = i & 63;
            w_s[0][i] = Wl[(kt + kr) * 64 + kc];
            w_s[1][i] = Wr[(kt + kr) * 64 + kc];
        }
        __syncthreads();
#pragma unroll 2
        for (int k4 = 0; k4 < 64; k4 += 4) {
            float w0 = w_s[half][(k4 + 0) * 64 + col];
            float w1 = w_s[half][(k4 + 1) * 64 + col];
            float w2 = w_s[half][(k4 + 2) * 64 + col];
            float w3 = w_s[half][(k4 + 3) * 64 + col];
#pragma unroll
            for (int r = 0; r < 8; ++r) {
                const float4 xv = *(const float4*)&x_s[rh * 8 + r][kt + k4];
                acc[r] += xv.x * w0 + xv.y * w1 + xv.z * w2 + xv.w * w3;
            }
        }
    }

    const float bias = b[col];
#pragma unroll
    for (int r = 0; r < 8; ++r) {
        int row = row0 + rh * 8 + r;
        if (half) z[row * 64 + col] = acc[r] + bias;
        else      yl[row * 64 + col] = f2b(acc[r]);
    }
}

// ---------------------------------------------------------------------------
// Pull-mode aggregation + finish, fused: one wave per dst row, lane = feature.
// yl is bf16 -> 128B per gathered row (half the R5 traffic).
__global__ __launch_bounds__(256) void gather_kernel(
    const int* __restrict__ rowptr, const int2* __restrict__ edgeA,
    const unsigned short* __restrict__ yl, const float* __restrict__ z,
    float* __restrict__ xout) {
    int row  = (blockIdx.x * 256 + threadIdx.x) >> 6;
    int lane = threadIdx.x & 63;
    int beg = rowptr[row], end = rowptr[row + 1];
    float acc = 0.f;
    int e = beg;
    for (; e + 4 <= end; e += 4) {
        int2 e0 = edgeA[e],     e1 = edgeA[e + 1];
        int2 e2 = edgeA[e + 2], e3 = edgeA[e + 3];
        float v0 = b2f(yl[e0.x * 64 + lane]), v1 = b2f(yl[e1.x * 64 + lane]);
        float v2 = b2f(yl[e2.x * 64 + lane]), v3 = b2f(yl[e3.x * 64 + lane]);
        acc += v0 * __builtin_bit_cast(float, e0.y);
        acc += v1 * __builtin_bit_cast(float, e1.y);
        acc += v2 * __builtin_bit_cast(float, e2.y);
        acc += v3 * __builtin_bit_cast(float, e3.y);
    }
    for (; e < end; ++e) {
        int2 ee = edgeA[e];
        acc += b2f(yl[ee.x * 64 + lane]) * __builtin_bit_cast(float, ee.y);
    }
    float deg = (float)(end - beg);
    float v = acc / fmaxf(deg, 1.f) + z[row * 64 + lane];
    xout[row * 64 + lane] = fmaxf(v, 0.f);
}

// ---------------------------------------------------------------------------
// Final: logits = [x1|x2|x3] @ Wlin + blin; out = log_softmax(logits).
// bf16 MFMA GEMM: block = 64 rows (4 waves x 16), N padded 40->48, K=192.
// A-layout: A[m=lane&15][k=(lane>>4)*8+j]; C/D: col=lane&15, row=quad*4+reg.
__global__ __launch_bounds__(256) void final_kernel(
    const float* __restrict__ x1, const float* __restrict__ x2,
    const float* __restrict__ x3, const float* __restrict__ Wlin,
    const float* __restrict__ blin, float* __restrict__ out) {
    __shared__ unsigned short xs[64 * 200];   // 64 rows x 192 (stride 200)
    __shared__ unsigned short wt[48 * 200];   // Wlin^T, zero-padded classes
    __shared__ float lg[4][16][49];           // per-wave logits
    __shared__ float blin_s[48];

    const int tid  = threadIdx.x;
    const int row0 = blockIdx.x * 64;

    for (int i = tid; i < 48 * 200; i += 256) wt[i] = 0;
    if (tid < 48) blin_s[tid] = (tid < 40) ? blin[tid] : 0.f;
    __syncthreads();  // zeros visible before sparse overwrite below
    for (int i = tid; i < 192 * 40; i += 256) {
        int k = i / 40, n = i % 40;
        wt[n * 200 + k] = f2b(Wlin[i]);
    }
    for (int i = tid; i < 64 * 64; i += 256) {
        int r = i >> 6, c = i & 63;
        int grow = row0 + r;
        bool ok = grow < Nn;
        xs[r * 200 + c]       = ok ? f2b(x1[grow * 64 + c]) : 0;
        xs[r * 200 + 64 + c]  = ok ? f2b(x2[grow * 64 + c]) : 0;
        xs[r * 200 + 128 + c] = ok ? f2b(x3[grow * 64 + c]) : 0;
    }
    __syncthreads();

    const int wv   = tid >> 6;
    const int lane = tid & 63;
    const int l15  = lane & 15;
    const int quad = lane >> 4;

    short8 a[6];
    const unsigned short* arow = xs + (wv * 16 + l15) * 200 + quad * 8;
#pragma unroll
    for (int ks = 0; ks < 6; ++ks) a[ks] = *(const short8*)(arow + ks * 32);

#pragma unroll
    for (int nt = 0; nt < 3; ++nt) {
        f32x4 acc = {0.f, 0.f, 0.f, 0.f};
        const unsigned short* brow = wt + (nt * 16 + l15) * 200 + quad * 8;
#pragma unroll
        for (int ks = 0; ks < 6; ++ks) {
            short8 b = *(const short8*)(brow + ks * 32);
            acc = __builtin_amdgcn_mfma_f32_16x16x32_bf16(a[ks], b, acc, 0, 0, 0);
        }
#pragma unroll
        for (int reg = 0; reg < 4; ++reg)
            lg[wv][quad * 4 + reg][nt * 16 + l15] = acc[reg];
    }
    // intra-wave LDS write->read: compiler inserts lgkmcnt wait; no barrier.

    // log_softmax: 4 lanes per row, 10 classes each
    const int r    = l15;
    const int part = quad;           // class chunk part*10 .. part*10+9
    float v[10];
    float mx = -INFINITY;
#pragma unroll
    for (int j = 0; j < 10; ++j) {
        v[j] = lg[wv][r][part * 10 + j] + blin_s[part * 10 + j];
        mx = fmaxf(mx, v[j]);
    }
    mx = fmaxf(mx, __shfl_xor(mx, 16));
    mx = fmaxf(mx, __shfl_xor(mx, 32));
    float s = 0.f;
#pragma unroll
    for (int j = 0; j < 10; ++j) s += expf(v[j] - mx);
    s += __shfl_xor(s, 16);
    s += __shfl_xor(s, 32);
    float lse = mx + logf(s);
    int grow = row0 + wv * 16 + r;
    if (grow < Nn) {
#pragma unroll
        for (int j = 0; j < 10; ++j)
            out[grow * NCLS + part * 10 + j] = v[j] - lse;
    }
}

// ---------------------------------------------------------------------------
extern "C" void kernel_launch(void* const* d_in, const int* in_sizes, int n_in,
                              void* d_out, int out_size, void* d_ws, size_t ws_size,
                              hipStream_t stream) {
    const float* x0  = (const float*)d_in[0];
    const int*   ei  = (const int*)d_in[1];
    const float* ew  = (const float*)d_in[2];
    const float* W1l = (const float*)d_in[3];
    const float* W1r = (const float*)d_in[4];
    const float* b1  = (const float*)d_in[5];
    const float* W2l = (const float*)d_in[6];
    const float* W2r = (const float*)d_in[7];
    const float* b2  = (const float*)d_in[8];
    const float* W3l = (const float*)d_in[9];
    const float* W3r = (const float*)d_in[10];
    const float* b3  = (const float*)d_in[11];
    const float* Wlin = (const float*)d_in[12];
    const float* blin = (const float*)d_in[13];
    float* out = (float*)d_out;

    const int* src = ei;       // edge_index[0]
    const int* dst = ei + Ee;  // edge_index[1]

    // Workspace layout (4-byte elements; edgeA 8B-aligned by construction)
    const size_t N64 = (size_t)Nn * 64;
    char* ws = (char*)d_ws;
    int*   cnt    = (int*)ws;                       // 50048
    int*   rowptr = cnt + 50048;                    // 50048 (Nn+1 used)
    int*   cursor = rowptr + 50048;                 // 50048
    int*   bsum   = cursor + 50048;                 // 256 (196 used)
    int2*  edgeA  = (int2*)(bsum + 256);            // Ee (8B each)
    unsigned short* yl = (unsigned short*)(edgeA + Ee);  // N64 bf16 (6.4MB)
    float* zb     = (float*)(yl + N64);             // N64 fp32
    float* x1     = zb + N64;                       // N64
    float* x2     = x1 + N64;                       // N64
    float* x3     = x2 + N64;                       // N64

    const int eblocks     = (Ee + 255) / 256;
    const int gemm_blocks = Nn / 16;       // exact
    const int row_blocks  = Nn / 4;        // gather: 4 rows/block, exact
    const int fin_blocks  = (Nn + 63) / 64;

    // ---- CSR build (per call; ws is re-poisoned) ----
    hipMemsetAsync(cnt, 0, Nn * sizeof(int), stream);
    count_kernel<<<eblocks, 256, 0, stream>>>(dst, cnt);
    scanA_kernel<<<SCAN_BLOCKS, 256, 0, stream>>>(cnt, rowptr, bsum);
    scanC_kernel<<<SCAN_BLOCKS, 256, 0, stream>>>(rowptr, bsum, cursor);
    fill_kernel<<<eblocks, 256, 0, stream>>>(src, dst, ew, cursor, edgeA);

    // ---- layer 1 (K = 128) ----
    gemm2_kernel<FIN><<<gemm_blocks, 256, 0, stream>>>(x0, W1l, W1r, b1, yl, zb);
    gather_kernel<<<row_blocks, 256, 0, stream>>>(rowptr, edgeA, yl, zb, x1);

    // ---- layer 2 (K = 64) ----
    gemm2_kernel<HID><<<gemm_blocks, 256, 0, stream>>>(x1, W2l, W2r, b2, yl, zb);
    gather_kernel<<<row_blocks, 256, 0, stream>>>(rowptr, edgeA, yl, zb, x2);

    // ---- layer 3 (K = 64) ----
    gemm2_kernel<HID><<<gemm_blocks, 256, 0, stream>>>(x2, W3l, W3r, b3, yl, zb);
    gather_kernel<<<row_blocks, 256, 0, stream>>>(rowptr, edgeA, yl, zb, x3);

    // ---- final linear + log_softmax (bf16 MFMA) ----
    final_kernel<<<fin_blocks, 256, 0, stream>>>(x1, x2, x3, Wlin, blin, out);
}